// Round 7
// baseline (26.175 us; speedup 1.0000x reference)
//
#include <hip/hip_runtime.h>

// Rydberg Hamiltonian apply: out[k] = diag(k)*state[k] + sum_b c_b * state[k ^ (1<<b)]
// N_QUBITS=22, DIM=2^22. Element bit b <-> qubit (21-b). c_b = 0.5*rabi[21-b].
//
// Single kernel, 512 blocks x 512 threads, 2 blocks/CU (VGPR <= 128):
//  - bits 0..1  : register permutes of own float4
//  - bits 2..12 : partners from 32 KB LDS tile
//  - bits 13..21: ALL 9 far partners ping-pong prefetched ONE CHUNK AHEAD
//  - diag: per-thread register dlo (4 vals, chunk-invariant) + per-block CJ/S4 tables
//  - rabi coeffs in SGPRs (readfirstlane); diag tables doubled, final *0.5
//  - out stored non-temporally (write-once)
// LDS total ~34 KB (static limit is 64 KB — round-6 crash was 75 KB).

#define THREADS 512
#define NBLK 512

typedef float fvec4 __attribute__((ext_vector_type(4)));

__device__ __forceinline__ int uidx(int i, int j) {
    // np.triu_indices(22, k=1) row-major flatten, i<j
    return i * (43 - i) / 2 + (j - i - 1);
}

__device__ __forceinline__ float to_sgpr(float x) {
    return __uint_as_float(__builtin_amdgcn_readfirstlane(__float_as_uint(x)));
}

__global__ __launch_bounds__(THREADS, 4) void ryd_kernel(
        const float* __restrict__ state, const float* __restrict__ rabi,
        const float* __restrict__ detune, const float* __restrict__ U,
        float* __restrict__ out) {
    __shared__ float4 tileS[2048];               // 32 KB state tile (element bits 0..12)
    __shared__ float Us[231];
    __shared__ float dets[22];
    __shared__ __align__(16) float CJ2[4][12];   // doubled cross terms (rows 48B, aligned)
    __shared__ float S42[4];                     // doubled hi-diag

    const float4* __restrict__ sF4 = (const float4*)state;
    float4* __restrict__ oF4 = (float4*)out;
    const unsigned t = threadIdx.x;
    const unsigned blk = blockIdx.x;
    // XCD-locality swizzle: 64 co-resident blocks of one XCD own a contiguous
    // 64-tile group; partner tiles tile^2^q, q<6 stay in-group (L2).
    const unsigned tile = ((blk & 7u) << 6) | (blk >> 3);   // [0,512)
    const unsigned tbase = tile * 2048u;

    // ---- stage U, detune into LDS ----
    if (t < 231u) Us[t] = U[t];
    else if (t < 253u) dets[t - 231u] = detune[t - 231u];

    // ---- issue own tile + ALL of chunk-0's far partners before table math ----
    float4 vtmp[4];
#pragma unroll
    for (int c = 0; c < 4; ++c)
        vtmp[c] = sF4[tbase + t + 512u * (unsigned)c];
    float4 pp[2][9];   // ping-pong prefetch, element bits 13..21
#pragma unroll
    for (int q = 0; q < 9; ++q)
        pp[0][q] = sF4[(tbase + t) ^ (2048u << q)];

    // ---- rabi -> SGPRs (raw values; final output halved once) ----
    float rg[22];
#pragma unroll
    for (int i = 0; i < 22; ++i) rg[i] = to_sgpr(rabi[i]);

    __syncthreads();    // Us/dets visible

    // ---- per-thread DOUBLED dlo registers; m11 = 4t + comp (chunk-invariant) ----
    float dl2x, dl2y, dl2z, dl2w;
    {
        float B = 0.f, R0 = 0.f, R1 = 0.f;
#pragma unroll
        for (int j2 = 0; j2 < 9; ++j2) {
            const int q2 = 19 - j2;            // m11 bit j2+2 <-> qubit 19-j2
            float ap = -dets[q2];
#pragma unroll
            for (int j1 = 0; j1 < j2; ++j1)
                ap += ((t >> j1) & 1u) ? Us[uidx(q2, 19 - j1)] : 0.f;
            const bool b2 = (t >> j2) & 1u;
            B  += b2 ? ap : 0.f;
            R0 += b2 ? Us[uidx(q2, 21)] : 0.f;  // pair with qubit 21 (m11 bit 0)
            R1 += b2 ? Us[uidx(q2, 20)] : 0.f;  // pair with qubit 20 (m11 bit 1)
        }
        const float w0 = -dets[21] + R0;
        const float w1 = -dets[20] + R1;
        const float u01 = Us[uidx(20, 21)];
        dl2x = B + B;
        dl2y = dl2x + w0 + w0;
        dl2z = dl2x + w1 + w1;
        dl2w = dl2y + w1 + w1 + u01 + u01;
    }
    // ---- per-block hi tables (doubled): hi11 = (tile<<2)|c, bit jh <-> qubit 10-jh ----
    if (t < 44u) {
        const int c = (int)t / 11, j = (int)t % 11;
        const unsigned h = (tile << 2) | (unsigned)c;
        float cc = 0.f;
        for (int jh = 0; jh < 11; ++jh)
            if ((h >> jh) & 1u) cc += Us[uidx(10 - jh, 21 - j)];
        CJ2[c][j] = cc + cc;
    } else if (t < 48u) {
        const int c = (int)t - 44;
        const unsigned h = (tile << 2) | (unsigned)c;
        float s = 0.f;
        for (int j2 = 0; j2 < 11; ++j2) {
            if ((h >> j2) & 1u) {
                s -= dets[10 - j2];
                for (int j1 = 0; j1 < j2; ++j1)
                    if ((h >> j1) & 1u) s += Us[uidx(10 - j2, 10 - j1)];
            }
        }
        S42[c] = s + s;
    }

    // ---- commit own tile to LDS ----
#pragma unroll
    for (int c = 0; c < 4; ++c)
        tileS[t + 512u * (unsigned)c] = vtmp[c];
    __syncthreads();   // tables + tile ready

#pragma unroll
    for (int c = 0; c < 4; ++c) {
        const unsigned f = t + 512u * (unsigned)c;   // f bits 9..10 == c; f&511 == t
        const unsigned F = tbase + f;
        // prefetch ALL of next chunk's far partners (one full chunk of lead time)
        if (c < 3) {
#pragma unroll
            for (int q = 0; q < 9; ++q)
                pp[(c + 1) & 1][q] = sF4[(F + 512u) ^ (2048u << q)];
        }
        // doubled diagonal
        const float4 cjA = *(const float4*)&CJ2[c][0];
        const float4 cjB = *(const float4*)&CJ2[c][4];
        const float4 cjC = *(const float4*)&CJ2[c][8];
        float s2 = S42[c];
        s2 += (t & 1u)   ? cjA.z : 0.f;   // lo bit j=0 of t -> cj2[2]
        s2 += (t & 2u)   ? cjA.w : 0.f;
        s2 += (t & 4u)   ? cjB.x : 0.f;
        s2 += (t & 8u)   ? cjB.y : 0.f;
        s2 += (t & 16u)  ? cjB.z : 0.f;
        s2 += (t & 32u)  ? cjB.w : 0.f;
        s2 += (t & 64u)  ? cjC.x : 0.f;
        s2 += (t & 128u) ? cjC.y : 0.f;
        s2 += (t & 256u) ? cjC.z : 0.f;
        const float d0 = s2 + dl2x;
        const float d1 = s2 + cjA.x + dl2y;
        const float d2 = s2 + cjA.y + dl2z;
        const float d3 = s2 + cjA.x + cjA.y + dl2w;
        const float4 v = tileS[f];
        float4 acc;
        acc.x = d0 * v.x; acc.y = d1 * v.y; acc.z = d2 * v.z; acc.w = d3 * v.w;
        // element bit 0 (qubit 21): swap within float pairs (raw rabi, halved at end)
        acc.x += rg[21] * v.y; acc.y += rg[21] * v.x;
        acc.z += rg[21] * v.w; acc.w += rg[21] * v.z;
        // element bit 1 (qubit 20): swap halves of the float4
        acc.x += rg[20] * v.z; acc.y += rg[20] * v.w;
        acc.z += rg[20] * v.x; acc.w += rg[20] * v.y;
        // element bits 2..12: partner float4 in LDS
#pragma unroll
        for (int b = 2; b <= 12; ++b) {
            const float rb = rg[21 - b];
            const float4 p = tileS[f ^ (1u << (b - 2))];
            acc.x += rb * p.x; acc.y += rb * p.y;
            acc.z += rb * p.z; acc.w += rb * p.w;
        }
        // element bits 13..21: prefetched far partners (bit 13+q <-> qubit 8-q)
#pragma unroll
        for (int q = 0; q < 9; ++q) {
            const float rb = rg[8 - q];
            const float4 p = pp[c & 1][q];
            acc.x += rb * p.x; acc.y += rb * p.y;
            acc.z += rb * p.z; acc.w += rb * p.w;
        }
        acc.x *= 0.5f; acc.y *= 0.5f; acc.z *= 0.5f; acc.w *= 0.5f;
        // write-once output: non-temporal, keep L2 for partner tiles
        union { float4 s4; fvec4 v4; } u;
        u.s4 = acc;
        __builtin_nontemporal_store(u.v4, reinterpret_cast<fvec4*>(oF4 + F));
    }
}

extern "C" void kernel_launch(void* const* d_in, const int* in_sizes, int n_in,
                              void* d_out, int out_size, void* d_ws, size_t ws_size,
                              hipStream_t stream) {
    const float* state  = (const float*)d_in[0];
    const float* rabi   = (const float*)d_in[1];
    const float* detune = (const float*)d_in[2];
    const float* U      = (const float*)d_in[3];
    float* out = (float*)d_out;
    (void)in_sizes; (void)n_in; (void)out_size; (void)d_ws; (void)ws_size;

    hipLaunchKernelGGL(ryd_kernel, dim3(NBLK), dim3(THREADS), 0, stream,
                       state, rabi, detune, U, out);
}

// Round 8
// 25.587 us; speedup vs baseline: 1.0230x; 1.0230x over previous
//
#include <hip/hip_runtime.h>

// Rydberg Hamiltonian apply: out[k] = diag(k)*state[k] + sum_b c_b * state[k ^ (1<<b)]
// N_QUBITS=22, DIM=2^22. Element bit b <-> qubit (21-b). c_b = 0.5*rabi[21-b].
//
// Single kernel, 512 blocks x 512 threads, 2 blocks/CU (VGPR budget ~100 < 128):
//  - bits 0..1  : register permutes of own float4
//  - bits 2..12 : partners from 32 KB LDS tile
//  - bits 16..21 (q=3..8): ping-pong prefetched ONE CHUNK AHEAD (pp[2][6], 48 VGPR)
//  - bits 13..15 (q=0..2): issued at chunk start, consumed LAST in chunk (pg[3])
//  - diag: per-thread register dlo (doubled) + per-block CJ2/S42 tables (doubled),
//    rabi in SGPRs (readfirstlane), single *0.5 at the end
//  - out stored non-temporally (write-once)
// Round-7 lesson: pp[2][9] (72 VGPR) spilled under the 128 cap -> 26 us. Depth 6 fits.

#define THREADS 512
#define NBLK 512

typedef float fvec4 __attribute__((ext_vector_type(4)));

__device__ __forceinline__ int uidx(int i, int j) {
    // np.triu_indices(22, k=1) row-major flatten, i<j
    return i * (43 - i) / 2 + (j - i - 1);
}

__device__ __forceinline__ float to_sgpr(float x) {
    return __uint_as_float(__builtin_amdgcn_readfirstlane(__float_as_uint(x)));
}

__global__ __launch_bounds__(THREADS, 4) void ryd_kernel(
        const float* __restrict__ state, const float* __restrict__ rabi,
        const float* __restrict__ detune, const float* __restrict__ U,
        float* __restrict__ out) {
    __shared__ float4 tileS[2048];               // 32 KB state tile (element bits 0..12)
    __shared__ float Us[231];
    __shared__ float dets[22];
    __shared__ __align__(16) float CJ2[4][12];   // doubled cross terms
    __shared__ float S42[4];                     // doubled hi-diag

    const float4* __restrict__ sF4 = (const float4*)state;
    float4* __restrict__ oF4 = (float4*)out;
    const unsigned t = threadIdx.x;
    const unsigned blk = blockIdx.x;
    // XCD-locality swizzle: 64 co-resident blocks of one XCD own a contiguous
    // 64-tile group; partner tiles tile^2^q, q<6 stay in-group (L2).
    const unsigned tile = ((blk & 7u) << 6) | (blk >> 3);   // [0,512)
    const unsigned tbase = tile * 2048u;

    // ---- stage U, detune into LDS ----
    if (t < 231u) Us[t] = U[t];
    else if (t < 253u) dets[t - 231u] = detune[t - 231u];

    // ---- issue own tile + chunk-0's deep-prefetch partners before table math ----
    float4 vtmp[4];
#pragma unroll
    for (int c = 0; c < 4; ++c)
        vtmp[c] = sF4[tbase + t + 512u * (unsigned)c];
    float4 pp[2][6];   // ping-pong prefetch, element bits 16..21 (q = 3..8)
#pragma unroll
    for (int q = 0; q < 6; ++q)
        pp[0][q] = sF4[(tbase + t) ^ (2048u << (q + 3))];

    // ---- rabi -> SGPRs (raw values; final output halved once) ----
    float rg[22];
#pragma unroll
    for (int i = 0; i < 22; ++i) rg[i] = to_sgpr(rabi[i]);

    __syncthreads();    // Us/dets visible

    // ---- per-thread DOUBLED dlo registers; m11 = 4t + comp (chunk-invariant) ----
    float dl2x, dl2y, dl2z, dl2w;
    {
        float B = 0.f, R0 = 0.f, R1 = 0.f;
#pragma unroll
        for (int j2 = 0; j2 < 9; ++j2) {
            const int q2 = 19 - j2;            // m11 bit j2+2 <-> qubit 19-j2
            float ap = -dets[q2];
#pragma unroll
            for (int j1 = 0; j1 < j2; ++j1)
                ap += ((t >> j1) & 1u) ? Us[uidx(q2, 19 - j1)] : 0.f;
            const bool b2 = (t >> j2) & 1u;
            B  += b2 ? ap : 0.f;
            R0 += b2 ? Us[uidx(q2, 21)] : 0.f;  // pair with qubit 21 (m11 bit 0)
            R1 += b2 ? Us[uidx(q2, 20)] : 0.f;  // pair with qubit 20 (m11 bit 1)
        }
        const float w0 = -dets[21] + R0;
        const float w1 = -dets[20] + R1;
        const float u01 = Us[uidx(20, 21)];
        dl2x = B + B;
        dl2y = dl2x + w0 + w0;
        dl2z = dl2x + w1 + w1;
        dl2w = dl2y + w1 + w1 + u01 + u01;
    }
    // ---- per-block hi tables (doubled): hi11 = (tile<<2)|c, bit jh <-> qubit 10-jh ----
    if (t < 44u) {
        const int c = (int)t / 11, j = (int)t % 11;
        const unsigned h = (tile << 2) | (unsigned)c;
        float cc = 0.f;
        for (int jh = 0; jh < 11; ++jh)
            if ((h >> jh) & 1u) cc += Us[uidx(10 - jh, 21 - j)];
        CJ2[c][j] = cc + cc;
    } else if (t < 48u) {
        const int c = (int)t - 44;
        const unsigned h = (tile << 2) | (unsigned)c;
        float s = 0.f;
        for (int j2 = 0; j2 < 11; ++j2) {
            if ((h >> j2) & 1u) {
                s -= dets[10 - j2];
                for (int j1 = 0; j1 < j2; ++j1)
                    if ((h >> j1) & 1u) s += Us[uidx(10 - j2, 10 - j1)];
            }
        }
        S42[c] = s + s;
    }

    // ---- commit own tile to LDS ----
#pragma unroll
    for (int c = 0; c < 4; ++c)
        tileS[t + 512u * (unsigned)c] = vtmp[c];
    __syncthreads();   // tables + tile ready

#pragma unroll
    for (int c = 0; c < 4; ++c) {
        const unsigned f = t + 512u * (unsigned)c;   // f bits 9..10 == c; f&511 == t
        const unsigned F = tbase + f;
        // near partners (element bits 13..15): issue now, consume LAST in chunk
        float4 pg[3];
#pragma unroll
        for (int q = 0; q < 3; ++q)
            pg[q] = sF4[F ^ (2048u << q)];
        // deep prefetch: NEXT chunk's far partners (element bits 16..21)
        if (c < 3) {
#pragma unroll
            for (int q = 0; q < 6; ++q)
                pp[(c + 1) & 1][q] = sF4[(F + 512u) ^ (2048u << (q + 3))];
        }
        // doubled diagonal
        const float4 cjA = *(const float4*)&CJ2[c][0];
        const float4 cjB = *(const float4*)&CJ2[c][4];
        const float4 cjC = *(const float4*)&CJ2[c][8];
        float s2 = S42[c];
        s2 += (t & 1u)   ? cjA.z : 0.f;   // lo bit j=0 of t -> cj2[2]
        s2 += (t & 2u)   ? cjA.w : 0.f;
        s2 += (t & 4u)   ? cjB.x : 0.f;
        s2 += (t & 8u)   ? cjB.y : 0.f;
        s2 += (t & 16u)  ? cjB.z : 0.f;
        s2 += (t & 32u)  ? cjB.w : 0.f;
        s2 += (t & 64u)  ? cjC.x : 0.f;
        s2 += (t & 128u) ? cjC.y : 0.f;
        s2 += (t & 256u) ? cjC.z : 0.f;
        const float d0 = s2 + dl2x;
        const float d1 = s2 + cjA.x + dl2y;
        const float d2 = s2 + cjA.y + dl2z;
        const float d3 = s2 + cjA.x + cjA.y + dl2w;
        const float4 v = tileS[f];
        float4 acc;
        acc.x = d0 * v.x; acc.y = d1 * v.y; acc.z = d2 * v.z; acc.w = d3 * v.w;
        // element bit 0 (qubit 21): swap within float pairs (raw rabi, halved at end)
        acc.x += rg[21] * v.y; acc.y += rg[21] * v.x;
        acc.z += rg[21] * v.w; acc.w += rg[21] * v.z;
        // element bit 1 (qubit 20): swap halves of the float4
        acc.x += rg[20] * v.z; acc.y += rg[20] * v.w;
        acc.z += rg[20] * v.x; acc.w += rg[20] * v.y;
        // element bits 16..21: prefetched last chunk (arrived long ago)
#pragma unroll
        for (int q = 0; q < 6; ++q) {
            const float rb = rg[5 - q];              // bit 16+q <-> qubit 5-q
            const float4 p = pp[c & 1][q];
            acc.x += rb * p.x; acc.y += rb * p.y;
            acc.z += rb * p.z; acc.w += rb * p.w;
        }
        // element bits 2..12: partner float4 in LDS (covers pg latency)
#pragma unroll
        for (int b = 2; b <= 12; ++b) {
            const float rb = rg[21 - b];
            const float4 p = tileS[f ^ (1u << (b - 2))];
            acc.x += rb * p.x; acc.y += rb * p.y;
            acc.z += rb * p.z; acc.w += rb * p.w;
        }
        // element bits 13..15: issued at chunk start (~250+ cyc lead)
#pragma unroll
        for (int q = 0; q < 3; ++q) {
            const float rb = rg[8 - q];              // bit 13+q <-> qubit 8-q
            const float4 p = pg[q];
            acc.x += rb * p.x; acc.y += rb * p.y;
            acc.z += rb * p.z; acc.w += rb * p.w;
        }
        acc.x *= 0.5f; acc.y *= 0.5f; acc.z *= 0.5f; acc.w *= 0.5f;
        // write-once output: non-temporal, keep L2 for partner tiles
        union { float4 s4; fvec4 v4; } u;
        u.s4 = acc;
        __builtin_nontemporal_store(u.v4, reinterpret_cast<fvec4*>(oF4 + F));
    }
}

extern "C" void kernel_launch(void* const* d_in, const int* in_sizes, int n_in,
                              void* d_out, int out_size, void* d_ws, size_t ws_size,
                              hipStream_t stream) {
    const float* state  = (const float*)d_in[0];
    const float* rabi   = (const float*)d_in[1];
    const float* detune = (const float*)d_in[2];
    const float* U      = (const float*)d_in[3];
    float* out = (float*)d_out;
    (void)in_sizes; (void)n_in; (void)out_size; (void)d_ws; (void)ws_size;

    hipLaunchKernelGGL(ryd_kernel, dim3(NBLK), dim3(THREADS), 0, stream,
                       state, rabi, detune, U, out);
}

// Round 9
// 25.007 us; speedup vs baseline: 1.0467x; 1.0232x over previous
//
#include <hip/hip_runtime.h>

// Rydberg Hamiltonian apply: out[k] = diag(k)*state[k] + sum_b c_b * state[k ^ (1<<b)]
// N_QUBITS=22, DIM=2^22. Element bit b <-> qubit (21-b). c_b = 0.5*rabi[21-b].
//
// Round-5 skeleton (best known: 20.9 us) + vmcnt-stream hygiene:
//  vmcnt retires IN ORDER, so slow ops must not be issued ahead of fast ones
//  that are consumed sooner.
//  1) per chunk: issue the 6 L2 partners BEFORE the 3 next-chunk L3 prefetches
//  2) defer all output stores to kernel end (no store in front of load consumption)
// Everything else identical to round 5: 512x512, 2 blocks/CU, XCD swizzle,
// 32KB tile (bits 0..12 LDS), dloS table w/ cheap build, NT stores.

#define THREADS 512
#define NBLK 512

typedef float fvec4 __attribute__((ext_vector_type(4)));

__device__ __forceinline__ int uidx(int i, int j) {
    // np.triu_indices(22, k=1) row-major flatten, i<j
    return i * (43 - i) / 2 + (j - i - 1);
}

__global__ __launch_bounds__(THREADS, 4) void ryd_kernel(
        const float* __restrict__ state, const float* __restrict__ rabi,
        const float* __restrict__ detune, const float* __restrict__ U,
        float* __restrict__ out) {
    __shared__ float4 tileS[2048];               // 32 KB state tile (element bits 0..12)
    __shared__ __align__(16) float dloS[2048];   // 8 KB diag table over element bits 0..10
    __shared__ float Us[231];
    __shared__ float dets[22];
    __shared__ float CJ[4][11];
    __shared__ float S4v[4];

    const float4* __restrict__ sF4 = (const float4*)state;
    float4* __restrict__ oF4 = (float4*)out;
    const unsigned t = threadIdx.x;
    const unsigned blk = blockIdx.x;
    // XCD-locality swizzle: 64 co-resident blocks of one XCD own a contiguous
    // 64-tile group; partner tiles tile^2^q, q<6 stay in-group (L2).
    const unsigned tile = ((blk & 7u) << 6) | (blk >> 3);   // [0,512)
    const unsigned tbase = tile * 2048u;

    // ---- stage U, detune into LDS ----
    if (t < 231u) Us[t] = U[t];
    else if (t < 253u) dets[t - 231u] = detune[t - 231u];

    // ---- issue own-tile loads + chunk-0's L3 partner loads BEFORE table math ----
    float4 vreg[4];
#pragma unroll
    for (int c = 0; c < 4; ++c)
        vreg[c] = sF4[tbase + t + 512u * (unsigned)c];
    float4 pgl[2][3];   // ping-pong prefetch for element bits 19..21 (b = 6..8)
#pragma unroll
    for (int b = 6; b < 9; ++b)
        pgl[0][b - 6] = sF4[(tbase + t) ^ (2048u << b)];

    __syncthreads();    // Us/dets visible

    // ---- dlo table over element bits 0..10 (bit j <-> qubit 21-j) ----
    // base over bits 0..8 (= t), analytic extension for bits 9,10.
    {
        float base = 0.f, R9 = 0.f, R10 = 0.f;
#pragma unroll
        for (int j2 = 0; j2 < 9; ++j2) {
            if ((t >> j2) & 1u) {
                base -= dets[21 - j2];
#pragma unroll
                for (int j1 = 0; j1 < j2; ++j1)
                    if ((t >> j1) & 1u) base += Us[uidx(21 - j2, 21 - j1)];
                R9  += Us[uidx(12, 21 - j2)];   // pair (qubit 12, qubit 21-j2)
                R10 += Us[uidx(11, 21 - j2)];   // pair (qubit 11, qubit 21-j2)
            }
        }
        const float w9  = -dets[12];            // bit 9  <-> qubit 12
        const float w10 = -dets[11];            // bit 10 <-> qubit 11
        const float u910 = Us[uidx(11, 12)];
        dloS[t]         = base;
        dloS[t + 512u]  = base + w9 + R9;
        dloS[t + 1024u] = base + w10 + R10;
        dloS[t + 1536u] = base + w9 + R9 + w10 + R10 + u910;
    }
    // ---- per-block hi tables: hi11 = (tile<<2)|c, bit jh <-> qubit 10-jh ----
    if (t < 44u) {
        const int c = (int)t / 11, j = (int)t % 11;
        const unsigned h = (tile << 2) | (unsigned)c;
        float cc = 0.f;
        for (int jh = 0; jh < 11; ++jh)
            if ((h >> jh) & 1u) cc += Us[uidx(10 - jh, 21 - j)];
        CJ[c][j] = cc;
    } else if (t < 48u) {
        const int c = (int)t - 44;
        const unsigned h = (tile << 2) | (unsigned)c;
        float s = 0.f;
        for (int j2 = 0; j2 < 11; ++j2) {
            if ((h >> j2) & 1u) {
                s -= dets[10 - j2];
                for (int j1 = 0; j1 < j2; ++j1)
                    if ((h >> j1) & 1u) s += Us[uidx(10 - j2, 10 - j1)];
            }
        }
        S4v[c] = s;
    }

    // ---- commit own tile to LDS ----
#pragma unroll
    for (int c = 0; c < 4; ++c)
        tileS[t + 512u * (unsigned)c] = vreg[c];
    __syncthreads();   // tables + tile ready

    const float r0 = 0.5f * rabi[21];
    const float r1 = 0.5f * rabi[20];
    float cb[9];
#pragma unroll
    for (int b = 0; b < 9; ++b) cb[b] = 0.5f * rabi[8 - b];  // bit 13+b <-> qubit 8-b

    float4 accOut[4];   // deferred outputs (overlays dying vreg lifetime)
#pragma unroll
    for (int c = 0; c < 4; ++c) {
        const unsigned f = t + 512u * (unsigned)c;   // f bits 9..10 == c
        const unsigned F = tbase + f;
        // (1) in-chunk same-XCD (L2) partners FIRST: their retire must not be
        //     gated by younger-but-slower L3 issues (vmcnt retires in order)
        float4 pg[6];
#pragma unroll
        for (int b = 0; b < 6; ++b)
            pg[b] = sF4[F ^ (2048u << b)];
        // then prefetch NEXT chunk's cross-XCD (L3) partners (full chunk of lead)
        if (c < 3) {
#pragma unroll
            for (int b = 6; b < 9; ++b)
                pgl[(c + 1) & 1][b - 6] = sF4[(F + 512u) ^ (2048u << b)];
        }

        float cj[11];
#pragma unroll
        for (int j = 0; j < 11; ++j) cj[j] = CJ[c][j];
        float s = S4v[c];
        const unsigned m = f & 511u;                 // element bits 2..10
#pragma unroll
        for (int j = 0; j < 9; ++j)
            s += ((m >> j) & 1u) ? cj[j + 2] : 0.f;
        const float4 dl = ((const float4*)dloS)[m];  // element bits 0..1 in comps
        const float4 v = vreg[c];
        const float d0 = s + dl.x;
        const float d1 = s + cj[0] + dl.y;
        const float d2 = s + cj[1] + dl.z;
        const float d3 = s + cj[0] + cj[1] + dl.w;
        float4 acc;
        acc.x = d0 * v.x; acc.y = d1 * v.y; acc.z = d2 * v.z; acc.w = d3 * v.w;
        // element bit 0 (qubit 21): swap within float pairs
        acc.x += r0 * v.y; acc.y += r0 * v.x; acc.z += r0 * v.w; acc.w += r0 * v.z;
        // element bit 1 (qubit 20): swap halves of the float4
        acc.x += r1 * v.z; acc.y += r1 * v.w; acc.z += r1 * v.x; acc.w += r1 * v.y;
        // element bits 2..12: partner float4 in LDS (covers pg latency)
#pragma unroll
        for (int b = 2; b <= 12; ++b) {
            const float rb = 0.5f * rabi[21 - b];
            const float4 p = tileS[f ^ (1u << (b - 2))];
            acc.x += rb * p.x; acc.y += rb * p.y; acc.z += rb * p.z; acc.w += rb * p.w;
        }
        // element bits 13..18: in-chunk L2 partners
#pragma unroll
        for (int b = 0; b < 6; ++b) {
            acc.x += cb[b] * pg[b].x; acc.y += cb[b] * pg[b].y;
            acc.z += cb[b] * pg[b].z; acc.w += cb[b] * pg[b].w;
        }
        // element bits 19..21: prefetched L3 partners (issued one chunk ago)
#pragma unroll
        for (int q = 0; q < 3; ++q) {
            const float4 p = pgl[c & 1][q];
            acc.x += cb[6 + q] * p.x; acc.y += cb[6 + q] * p.y;
            acc.z += cb[6 + q] * p.z; acc.w += cb[6 + q] * p.w;
        }
        // (2) defer the store: keep slow store-acks out of the load stream
        accOut[c] = acc;
    }

    // ---- drain: all 4 NT stores at the end (write-once output) ----
#pragma unroll
    for (int c = 0; c < 4; ++c) {
        union { float4 s4; fvec4 v4; } u;
        u.s4 = accOut[c];
        __builtin_nontemporal_store(
            u.v4, reinterpret_cast<fvec4*>(oF4 + tbase + t + 512u * (unsigned)c));
    }
}

extern "C" void kernel_launch(void* const* d_in, const int* in_sizes, int n_in,
                              void* d_out, int out_size, void* d_ws, size_t ws_size,
                              hipStream_t stream) {
    const float* state  = (const float*)d_in[0];
    const float* rabi   = (const float*)d_in[1];
    const float* detune = (const float*)d_in[2];
    const float* U      = (const float*)d_in[3];
    float* out = (float*)d_out;
    (void)in_sizes; (void)n_in; (void)out_size; (void)d_ws; (void)ws_size;

    hipLaunchKernelGGL(ryd_kernel, dim3(NBLK), dim3(THREADS), 0, stream,
                       state, rabi, detune, U, out);
}

// Round 10
// 21.088 us; speedup vs baseline: 1.2412x; 1.1858x over previous
//
#include <hip/hip_runtime.h>

// Rydberg Hamiltonian apply: out[k] = diag(k)*state[k] + sum_b c_b * state[k ^ (1<<b)]
// N_QUBITS=22, DIM=2^22. Element bit b <-> qubit (21-b). c_b = 0.5*rabi[21-b].
//
// EXACT round-5 source (best known: 20.9 us) with ONE change:
//   per chunk, the 6 in-chunk L2 partner loads are issued BEFORE the 3
//   next-chunk L3 prefetches (vmcnt retires in order; don't queue the
//   soon-consumed L2 loads behind fresh ~600-cycle L3 issues).
// No deferred stores (R9's accOut[4] added ~16 VGPR near the 128 cap).
// Structure: 512x512, 2 blocks/CU, XCD swizzle, 32KB tile (bits 0..12 LDS),
// dloS table w/ analytic bits-9/10 build, ping-pong L3 prefetch, NT stores.

#define THREADS 512
#define NBLK 512

typedef float fvec4 __attribute__((ext_vector_type(4)));

__device__ __forceinline__ int uidx(int i, int j) {
    // np.triu_indices(22, k=1) row-major flatten, i<j
    return i * (43 - i) / 2 + (j - i - 1);
}

__global__ __launch_bounds__(THREADS, 4) void ryd_kernel(
        const float* __restrict__ state, const float* __restrict__ rabi,
        const float* __restrict__ detune, const float* __restrict__ U,
        float* __restrict__ out) {
    __shared__ float4 tileS[2048];               // 32 KB state tile (element bits 0..12)
    __shared__ __align__(16) float dloS[2048];   // 8 KB diag table over element bits 0..10
    __shared__ float Us[231];
    __shared__ float dets[22];
    __shared__ float CJ[4][11];
    __shared__ float S4v[4];

    const float4* __restrict__ sF4 = (const float4*)state;
    float4* __restrict__ oF4 = (float4*)out;
    const unsigned t = threadIdx.x;
    const unsigned blk = blockIdx.x;
    // XCD-locality swizzle: the 64 co-resident blocks of one XCD own a
    // contiguous 64-tile group; partner tiles tile^2^q, q<6 stay in-group (L2).
    const unsigned tile = ((blk & 7u) << 6) | (blk >> 3);   // [0,512)
    const unsigned tbase = tile * 2048u;

    // ---- stage U, detune into LDS ----
    if (t < 231u) Us[t] = U[t];
    else if (t < 253u) dets[t - 231u] = detune[t - 231u];

    // ---- issue own-tile loads + chunk-0's L3 partner loads BEFORE table math ----
    float4 vreg[4];
#pragma unroll
    for (int c = 0; c < 4; ++c)
        vreg[c] = sF4[tbase + t + 512u * (unsigned)c];
    float4 pgl[2][3];   // ping-pong prefetch for element bits 19..21 (b = 6..8)
#pragma unroll
    for (int b = 6; b < 9; ++b)
        pgl[0][b - 6] = sF4[(tbase + t) ^ (2048u << b)];

    __syncthreads();    // Us/dets visible

    // ---- dlo table over element bits 0..10 (bit j <-> qubit 21-j) ----
    // base over bits 0..8 (= t), analytic extension for bits 9,10.
    {
        float base = 0.f, R9 = 0.f, R10 = 0.f;
#pragma unroll
        for (int j2 = 0; j2 < 9; ++j2) {
            if ((t >> j2) & 1u) {
                base -= dets[21 - j2];
#pragma unroll
                for (int j1 = 0; j1 < j2; ++j1)
                    if ((t >> j1) & 1u) base += Us[uidx(21 - j2, 21 - j1)];
                R9  += Us[uidx(12, 21 - j2)];   // pair (qubit 12, qubit 21-j2)
                R10 += Us[uidx(11, 21 - j2)];   // pair (qubit 11, qubit 21-j2)
            }
        }
        const float w9  = -dets[12];            // bit 9  <-> qubit 12
        const float w10 = -dets[11];            // bit 10 <-> qubit 11
        const float u910 = Us[uidx(11, 12)];
        dloS[t]         = base;
        dloS[t + 512u]  = base + w9 + R9;
        dloS[t + 1024u] = base + w10 + R10;
        dloS[t + 1536u] = base + w9 + R9 + w10 + R10 + u910;
    }
    // ---- per-block hi tables: hi11 = (tile<<2)|c, bit jh <-> qubit 10-jh ----
    if (t < 44u) {
        const int c = (int)t / 11, j = (int)t % 11;
        const unsigned h = (tile << 2) | (unsigned)c;
        float cc = 0.f;
        for (int jh = 0; jh < 11; ++jh)
            if ((h >> jh) & 1u) cc += Us[uidx(10 - jh, 21 - j)];
        CJ[c][j] = cc;
    } else if (t < 48u) {
        const int c = (int)t - 44;
        const unsigned h = (tile << 2) | (unsigned)c;
        float s = 0.f;
        for (int j2 = 0; j2 < 11; ++j2) {
            if ((h >> j2) & 1u) {
                s -= dets[10 - j2];
                for (int j1 = 0; j1 < j2; ++j1)
                    if ((h >> j1) & 1u) s += Us[uidx(10 - j2, 10 - j1)];
            }
        }
        S4v[c] = s;
    }

    // ---- commit own tile to LDS ----
#pragma unroll
    for (int c = 0; c < 4; ++c)
        tileS[t + 512u * (unsigned)c] = vreg[c];
    __syncthreads();   // tables + tile ready

    const float r0 = 0.5f * rabi[21];
    const float r1 = 0.5f * rabi[20];
    float cb[9];
#pragma unroll
    for (int b = 0; b < 9; ++b) cb[b] = 0.5f * rabi[8 - b];  // bit 13+b <-> qubit 8-b

#pragma unroll
    for (int c = 0; c < 4; ++c) {
        const unsigned f = t + 512u * (unsigned)c;   // f bits 9..10 == c
        const unsigned F = tbase + f;
        // in-chunk same-XCD (L2) partners FIRST (element bits 13..18):
        // their retire must not queue behind fresh slow L3 issues.
        float4 pg[6];
#pragma unroll
        for (int b = 0; b < 6; ++b)
            pg[b] = sF4[F ^ (2048u << b)];
        // then prefetch NEXT chunk's cross-XCD (L3) partners
        if (c < 3) {
#pragma unroll
            for (int b = 6; b < 9; ++b)
                pgl[(c + 1) & 1][b - 6] = sF4[(F + 512u) ^ (2048u << b)];
        }

        float cj[11];
#pragma unroll
        for (int j = 0; j < 11; ++j) cj[j] = CJ[c][j];
        float s = S4v[c];
        const unsigned m = f & 511u;                 // element bits 2..10
#pragma unroll
        for (int j = 0; j < 9; ++j)
            s += ((m >> j) & 1u) ? cj[j + 2] : 0.f;
        const float4 dl = ((const float4*)dloS)[m];  // element bits 0..1 in comps
        const float4 v = vreg[c];
        const float d0 = s + dl.x;
        const float d1 = s + cj[0] + dl.y;
        const float d2 = s + cj[1] + dl.z;
        const float d3 = s + cj[0] + cj[1] + dl.w;
        float4 acc;
        acc.x = d0 * v.x; acc.y = d1 * v.y; acc.z = d2 * v.z; acc.w = d3 * v.w;
        // element bit 0 (qubit 21): swap within float pairs
        acc.x += r0 * v.y; acc.y += r0 * v.x; acc.z += r0 * v.w; acc.w += r0 * v.z;
        // element bit 1 (qubit 20): swap halves of the float4
        acc.x += r1 * v.z; acc.y += r1 * v.w; acc.z += r1 * v.x; acc.w += r1 * v.y;
        // element bits 2..12: partner float4 in LDS (covers pg latency)
#pragma unroll
        for (int b = 2; b <= 12; ++b) {
            const float rb = 0.5f * rabi[21 - b];
            const float4 p = tileS[f ^ (1u << (b - 2))];
            acc.x += rb * p.x; acc.y += rb * p.y; acc.z += rb * p.z; acc.w += rb * p.w;
        }
        // element bits 13..18: in-chunk L2 partners
#pragma unroll
        for (int b = 0; b < 6; ++b) {
            acc.x += cb[b] * pg[b].x; acc.y += cb[b] * pg[b].y;
            acc.z += cb[b] * pg[b].z; acc.w += cb[b] * pg[b].w;
        }
        // element bits 19..21: prefetched L3 partners (issued one chunk ago)
#pragma unroll
        for (int q = 0; q < 3; ++q) {
            const float4 p = pgl[c & 1][q];
            acc.x += cb[6 + q] * p.x; acc.y += cb[6 + q] * p.y;
            acc.z += cb[6 + q] * p.z; acc.w += cb[6 + q] * p.w;
        }
        // write-once output: non-temporal, keep L2 for partner tiles
        union { float4 s4; fvec4 v4; } u;
        u.s4 = acc;
        __builtin_nontemporal_store(u.v4, reinterpret_cast<fvec4*>(oF4 + F));
    }
}

extern "C" void kernel_launch(void* const* d_in, const int* in_sizes, int n_in,
                              void* d_out, int out_size, void* d_ws, size_t ws_size,
                              hipStream_t stream) {
    const float* state  = (const float*)d_in[0];
    const float* rabi   = (const float*)d_in[1];
    const float* detune = (const float*)d_in[2];
    const float* U      = (const float*)d_in[3];
    float* out = (float*)d_out;
    (void)in_sizes; (void)n_in; (void)out_size; (void)d_ws; (void)ws_size;

    hipLaunchKernelGGL(ryd_kernel, dim3(NBLK), dim3(THREADS), 0, stream,
                       state, rabi, detune, U, out);
}

// Round 11
// 20.944 us; speedup vs baseline: 1.2498x; 1.0069x over previous
//
#include <hip/hip_runtime.h>

// Rydberg Hamiltonian apply: out[k] = diag(k)*state[k] + sum_b c_b * state[k ^ (1<<b)]
// N_QUBITS=22, DIM=2^22. Element bit b <-> qubit (21-b). c_b = 0.5*rabi[21-b].
//
// R10 base (21.1 us; == R5 20.9 within noise) with LDS-pipe cuts ONLY:
//  1) dl (dloS[t]) is chunk-invariant -> loaded once, not 4x
//  2) partner bits 11,12 are the thread's own other chunks (f^512 = vreg[c^1],
//     f^1024 = vreg[c^2]) -> register FMAs instead of 2 ds_reads per chunk
// ds_read_b128 per thread: 48 -> 37. No new registers, VMEM schedule untouched.
// Structure: 512x512, 2 blocks/CU, XCD swizzle, 32KB tile, ping-pong L3
// prefetch (bits 19..21), in-chunk L2 partners (bits 13..18), NT stores.

#define THREADS 512
#define NBLK 512

typedef float fvec4 __attribute__((ext_vector_type(4)));

__device__ __forceinline__ int uidx(int i, int j) {
    // np.triu_indices(22, k=1) row-major flatten, i<j
    return i * (43 - i) / 2 + (j - i - 1);
}

__global__ __launch_bounds__(THREADS, 4) void ryd_kernel(
        const float* __restrict__ state, const float* __restrict__ rabi,
        const float* __restrict__ detune, const float* __restrict__ U,
        float* __restrict__ out) {
    __shared__ float4 tileS[2048];               // 32 KB state tile (element bits 0..12)
    __shared__ __align__(16) float dloS[2048];   // 8 KB diag table over element bits 0..10
    __shared__ float Us[231];
    __shared__ float dets[22];
    __shared__ float CJ[4][11];
    __shared__ float S4v[4];

    const float4* __restrict__ sF4 = (const float4*)state;
    float4* __restrict__ oF4 = (float4*)out;
    const unsigned t = threadIdx.x;
    const unsigned blk = blockIdx.x;
    // XCD-locality swizzle: the 64 co-resident blocks of one XCD own a
    // contiguous 64-tile group; partner tiles tile^2^q, q<6 stay in-group (L2).
    const unsigned tile = ((blk & 7u) << 6) | (blk >> 3);   // [0,512)
    const unsigned tbase = tile * 2048u;

    // ---- stage U, detune into LDS ----
    if (t < 231u) Us[t] = U[t];
    else if (t < 253u) dets[t - 231u] = detune[t - 231u];

    // ---- issue own-tile loads + chunk-0's L3 partner loads BEFORE table math ----
    float4 vreg[4];
#pragma unroll
    for (int c = 0; c < 4; ++c)
        vreg[c] = sF4[tbase + t + 512u * (unsigned)c];
    float4 pgl[2][3];   // ping-pong prefetch for element bits 19..21 (b = 6..8)
#pragma unroll
    for (int b = 6; b < 9; ++b)
        pgl[0][b - 6] = sF4[(tbase + t) ^ (2048u << b)];

    __syncthreads();    // Us/dets visible

    // ---- dlo table over element bits 0..10 (bit j <-> qubit 21-j) ----
    // base over bits 0..8 (= t), analytic extension for bits 9,10.
    {
        float base = 0.f, R9 = 0.f, R10 = 0.f;
#pragma unroll
        for (int j2 = 0; j2 < 9; ++j2) {
            if ((t >> j2) & 1u) {
                base -= dets[21 - j2];
#pragma unroll
                for (int j1 = 0; j1 < j2; ++j1)
                    if ((t >> j1) & 1u) base += Us[uidx(21 - j2, 21 - j1)];
                R9  += Us[uidx(12, 21 - j2)];   // pair (qubit 12, qubit 21-j2)
                R10 += Us[uidx(11, 21 - j2)];   // pair (qubit 11, qubit 21-j2)
            }
        }
        const float w9  = -dets[12];            // bit 9  <-> qubit 12
        const float w10 = -dets[11];            // bit 10 <-> qubit 11
        const float u910 = Us[uidx(11, 12)];
        dloS[t]         = base;
        dloS[t + 512u]  = base + w9 + R9;
        dloS[t + 1024u] = base + w10 + R10;
        dloS[t + 1536u] = base + w9 + R9 + w10 + R10 + u910;
    }
    // ---- per-block hi tables: hi11 = (tile<<2)|c, bit jh <-> qubit 10-jh ----
    if (t < 44u) {
        const int c = (int)t / 11, j = (int)t % 11;
        const unsigned h = (tile << 2) | (unsigned)c;
        float cc = 0.f;
        for (int jh = 0; jh < 11; ++jh)
            if ((h >> jh) & 1u) cc += Us[uidx(10 - jh, 21 - j)];
        CJ[c][j] = cc;
    } else if (t < 48u) {
        const int c = (int)t - 44;
        const unsigned h = (tile << 2) | (unsigned)c;
        float s = 0.f;
        for (int j2 = 0; j2 < 11; ++j2) {
            if ((h >> j2) & 1u) {
                s -= dets[10 - j2];
                for (int j1 = 0; j1 < j2; ++j1)
                    if ((h >> j1) & 1u) s += Us[uidx(10 - j2, 10 - j1)];
            }
        }
        S4v[c] = s;
    }

    // ---- commit own tile to LDS ----
#pragma unroll
    for (int c = 0; c < 4; ++c)
        tileS[t + 512u * (unsigned)c] = vreg[c];
    __syncthreads();   // tables + tile ready

    const float r0 = 0.5f * rabi[21];
    const float r1 = 0.5f * rabi[20];
    const float r11 = 0.5f * rabi[10];   // element bit 11 partner (= own vreg[c^1])
    const float r12 = 0.5f * rabi[9];    // element bit 12 partner (= own vreg[c^2])
    float cb[9];
#pragma unroll
    for (int b = 0; b < 9; ++b) cb[b] = 0.5f * rabi[8 - b];  // bit 13+b <-> qubit 8-b

    // dl is chunk-invariant (m = f&511 = t for every chunk): load ONCE
    const float4 dl = ((const float4*)dloS)[t];   // element bits 0..1 in comps

#pragma unroll
    for (int c = 0; c < 4; ++c) {
        const unsigned f = t + 512u * (unsigned)c;   // f bits 9..10 == c
        const unsigned F = tbase + f;
        // in-chunk same-XCD (L2) partners FIRST (element bits 13..18):
        // their retire must not queue behind fresh slow L3 issues.
        float4 pg[6];
#pragma unroll
        for (int b = 0; b < 6; ++b)
            pg[b] = sF4[F ^ (2048u << b)];
        // then prefetch NEXT chunk's cross-XCD (L3) partners
        if (c < 3) {
#pragma unroll
            for (int b = 6; b < 9; ++b)
                pgl[(c + 1) & 1][b - 6] = sF4[(F + 512u) ^ (2048u << b)];
        }

        float cj[11];
#pragma unroll
        for (int j = 0; j < 11; ++j) cj[j] = CJ[c][j];
        float s = S4v[c];
#pragma unroll
        for (int j = 0; j < 9; ++j)
            s += ((t >> j) & 1u) ? cj[j + 2] : 0.f;   // element bits 2..10 (= t bits)
        const float4 v = vreg[c];
        const float d0 = s + dl.x;
        const float d1 = s + cj[0] + dl.y;
        const float d2 = s + cj[1] + dl.z;
        const float d3 = s + cj[0] + cj[1] + dl.w;
        float4 acc;
        acc.x = d0 * v.x; acc.y = d1 * v.y; acc.z = d2 * v.z; acc.w = d3 * v.w;
        // element bit 0 (qubit 21): swap within float pairs
        acc.x += r0 * v.y; acc.y += r0 * v.x; acc.z += r0 * v.w; acc.w += r0 * v.z;
        // element bit 1 (qubit 20): swap halves of the float4
        acc.x += r1 * v.z; acc.y += r1 * v.w; acc.z += r1 * v.x; acc.w += r1 * v.y;
        // element bits 11,12: partners are this thread's OTHER CHUNKS (registers)
        {
            const float4 pa = vreg[c ^ 1];
            const float4 pb = vreg[c ^ 2];
            acc.x += r11 * pa.x; acc.y += r11 * pa.y;
            acc.z += r11 * pa.z; acc.w += r11 * pa.w;
            acc.x += r12 * pb.x; acc.y += r12 * pb.y;
            acc.z += r12 * pb.z; acc.w += r12 * pb.w;
        }
        // element bits 2..10: partner float4 in LDS (covers pg latency)
#pragma unroll
        for (int b = 2; b <= 10; ++b) {
            const float rb = 0.5f * rabi[21 - b];
            const float4 p = tileS[f ^ (1u << (b - 2))];
            acc.x += rb * p.x; acc.y += rb * p.y; acc.z += rb * p.z; acc.w += rb * p.w;
        }
        // element bits 13..18: in-chunk L2 partners
#pragma unroll
        for (int b = 0; b < 6; ++b) {
            acc.x += cb[b] * pg[b].x; acc.y += cb[b] * pg[b].y;
            acc.z += cb[b] * pg[b].z; acc.w += cb[b] * pg[b].w;
        }
        // element bits 19..21: prefetched L3 partners (issued one chunk ago)
#pragma unroll
        for (int q = 0; q < 3; ++q) {
            const float4 p = pgl[c & 1][q];
            acc.x += cb[6 + q] * p.x; acc.y += cb[6 + q] * p.y;
            acc.z += cb[6 + q] * p.z; acc.w += cb[6 + q] * p.w;
        }
        // write-once output: non-temporal, keep L2 for partner tiles
        union { float4 s4; fvec4 v4; } u;
        u.s4 = acc;
        __builtin_nontemporal_store(u.v4, reinterpret_cast<fvec4*>(oF4 + F));
    }
}

extern "C" void kernel_launch(void* const* d_in, const int* in_sizes, int n_in,
                              void* d_out, int out_size, void* d_ws, size_t ws_size,
                              hipStream_t stream) {
    const float* state  = (const float*)d_in[0];
    const float* rabi   = (const float*)d_in[1];
    const float* detune = (const float*)d_in[2];
    const float* U      = (const float*)d_in[3];
    float* out = (float*)d_out;
    (void)in_sizes; (void)n_in; (void)out_size; (void)d_ws; (void)ws_size;

    hipLaunchKernelGGL(ryd_kernel, dim3(NBLK), dim3(THREADS), 0, stream,
                       state, rabi, detune, U, out);
}